// Round 2
// baseline (2153.994 us; speedup 1.0000x reference)
//
#include <hip/hip_runtime.h>
#include <hip/hip_bf16.h>

typedef __hip_bfloat16 bf16;
typedef unsigned short u16;
typedef unsigned int u32;

#define N_NODES 100000
#define N_EDGES 1200000
#define DIM 64
#define NG 128
#define NLAYERS 4
#define BN_EPS 1e-5f

// ---- workspace layout (float offsets) ----
#define WS_GSUM   0
#define WS_GSUMSQ 64
#define WS_AB     128     // [64] scale a, [64] shift s
#define WS_FLAG   256     // int: 0 = inputs are bf16, 1 = inputs are fp32
#define WS_WALL   320     // converted fp32 weights, 37952 floats
#define OFF_WEMB  0
#define OFF_BEMB  4096
#define OFF_W1    4160
#define OFF_B1    20544
#define OFF_GAMMA 20800
#define OFF_BETA  21056
#define OFF_W2    21312
#define OFF_B2    37696
#define W_TOTAL   37952
#define WS_AGG    38400                        // fp32 [N,64]
#define WS_H      (WS_AGG + N_NODES * DIM)     // bf16 [N,64] stored after agg
#define WS_NEED_BYTES ((size_t)WS_H * 4 + (size_t)N_NODES * DIM * 2)

__device__ __forceinline__ float b2f(bf16 v) { return __bfloat162float(v); }

// dual-dtype load: p is bf16* (flag=0) or float* (flag=1)
__device__ __forceinline__ float loadf(const void* p, long i, int flag) {
    if (flag) return ((const float*)p)[i];
    u32 w = ((u32)((const u16*)p)[i]) << 16;
    return __uint_as_float(w);
}

// ---- diagnostics: encode a value readably under both bf16 and fp32 reads ----
__global__ void k_diag(u32* out, float val) {
    if (threadIdx.x == 0 && blockIdx.x == 0) {
        bf16 b = __float2bfloat16(val);
        u16 bits;
        __builtin_memcpy(&bits, &b, 2);
        u32 w = ((u32)bits << 16) | bits;
        for (int i = 0; i < 8; i++) out[i] = w;
    }
}

// ---- dtype detection: fp32 data read as bf16 pairs has garbage even-halves ----
__global__ void k_detect(const void* x, int* flag) {
    if (threadIdx.x == 0 && blockIdx.x == 0) {
        const u16* u = (const u16*)x;
        int bad = 0;
        for (int i = 0; i < 512; i++) {
            float v = __uint_as_float(((u32)u[i]) << 16);
            if (!(fabsf(v) < 100.f)) bad++;   // catches NaN/Inf too
        }
        *flag = (bad > 16) ? 1 : 0;
    }
}

// ---- convert all weights to fp32 in ws ----
__global__ __launch_bounds__(256) void k_convert(const void* W_emb, const void* b_emb,
                                                 const void* W1, const void* b1,
                                                 const void* gamma, const void* beta,
                                                 const void* W2, const void* b2,
                                                 const int* flagp, float* dst) {
    int f = *flagp;
    for (int i = blockIdx.x * blockDim.x + threadIdx.x; i < W_TOTAL;
         i += gridDim.x * blockDim.x) {
        const void* p; int off;
        if (i < OFF_BEMB)       { p = W_emb; off = i; }
        else if (i < OFF_W1)    { p = b_emb; off = i - OFF_BEMB; }
        else if (i < OFF_B1)    { p = W1;    off = i - OFF_W1; }
        else if (i < OFF_GAMMA) { p = b1;    off = i - OFF_B1; }
        else if (i < OFF_BETA)  { p = gamma; off = i - OFF_GAMMA; }
        else if (i < OFF_W2)    { p = beta;  off = i - OFF_BETA; }
        else if (i < OFF_B2)    { p = W2;    off = i - OFF_W2; }
        else                    { p = b2;    off = i - OFF_B2; }
        dst[i] = loadf(p, off, f);
    }
}

// h[n][c] = sum_d x[n][d] * W[d][c] + b[c]   (h stored bf16)
__global__ __launch_bounds__(256) void k_embed(const void* __restrict__ x,
                                               const int* __restrict__ flagp,
                                               const float* __restrict__ Wf,
                                               const float* __restrict__ bf_,
                                               bf16* __restrict__ h) {
    __shared__ float Wl[DIM * DIM];
    __shared__ float bl[DIM];
    int tid = threadIdx.x;
    int f = *flagp;
    for (int i = tid; i < DIM * DIM; i += 256) Wl[i] = Wf[i];
    if (tid < DIM) bl[tid] = bf_[tid];
    __syncthreads();
    int lane = tid & 63, wv = tid >> 6;
    for (int row = blockIdx.x * 4 + wv; row < N_NODES; row += gridDim.x * 4) {
        float xv = loadf(x, (long)row * DIM + lane, f);
        float acc = bl[lane];
#pragma unroll
        for (int d = 0; d < DIM; d++) acc += __shfl(xv, d, 64) * Wl[d * DIM + lane];
        h[(long)row * DIM + lane] = __float2bfloat16(acc);
    }
}

// agg[dst] += h[src] over edges (agg fp32, pre-zeroed)
__global__ __launch_bounds__(256) void k_scatter(const int* __restrict__ ei,
                                                 const bf16* __restrict__ h,
                                                 float* __restrict__ agg) {
    int lane = threadIdx.x & 63;
    int wid = (blockIdx.x * 256 + threadIdx.x) >> 6;
    int nw = (gridDim.x * 256) >> 6;
    for (int e = wid; e < N_EDGES; e += nw) {
        int src = ei[e];
        int dst = ei[N_EDGES + e];
        atomicAdd(&agg[(long)dst * DIM + lane], b2f(h[(long)src * DIM + lane]));
    }
}

// z[n][c] = sum_d (h[n][d]+agg[n][d]) * W[d][c] + b[c]  (z overwrites agg, fp32)
// accumulates per-channel sum / sumsq for BN
__global__ __launch_bounds__(256) void k_gemm1(const bf16* __restrict__ h,
                                               float* __restrict__ z,
                                               const float* __restrict__ Wf,
                                               const float* __restrict__ bf_,
                                               float* __restrict__ gsum,
                                               float* __restrict__ gsumsq) {
    __shared__ float Wl[DIM * DIM];
    __shared__ float bl[DIM];
    __shared__ float psum[4][DIM];
    __shared__ float psumsq[4][DIM];
    int tid = threadIdx.x;
    int lane = tid & 63, wv = tid >> 6;
    for (int i = tid; i < DIM * DIM; i += 256) Wl[i] = Wf[i];
    if (tid < DIM) bl[tid] = bf_[tid];
    __syncthreads();
    float ls = 0.f, lq = 0.f;
    for (int row = blockIdx.x * 4 + wv; row < N_NODES; row += gridDim.x * 4) {
        float v = b2f(h[(long)row * DIM + lane]) + z[(long)row * DIM + lane];
        float acc = bl[lane];
#pragma unroll
        for (int d = 0; d < DIM; d++) acc += __shfl(v, d, 64) * Wl[d * DIM + lane];
        z[(long)row * DIM + lane] = acc;   // row owned by this wave: safe
        ls += acc;
        lq += acc * acc;
    }
    psum[wv][lane] = ls;
    psumsq[wv][lane] = lq;
    __syncthreads();
    if (tid < DIM) {
        atomicAdd(&gsum[tid], psum[0][tid] + psum[1][tid] + psum[2][tid] + psum[3][tid]);
        atomicAdd(&gsumsq[tid], psumsq[0][tid] + psumsq[1][tid] + psumsq[2][tid] + psumsq[3][tid]);
    }
}

// fold BN into affine a*x + s
__global__ void k_stats(const float* __restrict__ gsum, const float* __restrict__ gsumsq,
                        const float* __restrict__ gamma_f, const float* __restrict__ beta_f,
                        float* __restrict__ ab) {
    int c = threadIdx.x;
    if (c < DIM) {
        float inv_n = 1.0f / (float)N_NODES;
        float mu = gsum[c] * inv_n;
        float var = fmaxf(gsumsq[c] * inv_n - mu * mu, 0.f);
        float a = gamma_f[c] * rsqrtf(var + BN_EPS);
        ab[c] = a;
        ab[DIM + c] = beta_f[c] - mu * a;
    }
}

// h[n][c] = sum_d relu(a[d]*z[n][d]+s[d]) * W[d][c] + b[c]   (h stored bf16)
__global__ __launch_bounds__(256) void k_gemm2(const float* __restrict__ z,
                                               bf16* __restrict__ h,
                                               const float* __restrict__ Wf,
                                               const float* __restrict__ bf_,
                                               const float* __restrict__ ab) {
    __shared__ float Wl[DIM * DIM];
    __shared__ float bl[DIM], al[DIM], sl[DIM];
    int tid = threadIdx.x;
    int lane = tid & 63, wv = tid >> 6;
    for (int i = tid; i < DIM * DIM; i += 256) Wl[i] = Wf[i];
    if (tid < DIM) { bl[tid] = bf_[tid]; al[tid] = ab[tid]; sl[tid] = ab[DIM + tid]; }
    __syncthreads();
    for (int row = blockIdx.x * 4 + wv; row < N_NODES; row += gridDim.x * 4) {
        float v = z[(long)row * DIM + lane];
        v = fmaxf(al[lane] * v + sl[lane], 0.f);
        float acc = bl[lane];
#pragma unroll
        for (int d = 0; d < DIM; d++) acc += __shfl(v, d, 64) * Wl[d * DIM + lane];
        h[(long)row * DIM + lane] = __float2bfloat16(acc);
    }
}

// mean-pool per graph (batch sorted); dual-dtype output write
__global__ __launch_bounds__(256) void k_pool(const bf16* __restrict__ h,
                                              const int* __restrict__ batch,
                                              void* __restrict__ out, int rep,
                                              const int* __restrict__ flagp) {
    __shared__ float ps[4][DIM];
    int g = blockIdx.x;
    int tid = threadIdx.x, lane = tid & 63, wv = tid >> 6;
    int f = *flagp;
    int a = 0, bnd = N_NODES;
    while (a < bnd) { int m = (a + bnd) >> 1; if (batch[m] < g) a = m + 1; else bnd = m; }
    int lo = a;
    bnd = N_NODES;
    while (a < bnd) { int m = (a + bnd) >> 1; if (batch[m] < g + 1) a = m + 1; else bnd = m; }
    int hi = a;
    float s = 0.f;
    for (int r = lo + wv; r < hi; r += 4) s += b2f(h[(long)r * DIM + lane]);
    ps[wv][lane] = s;
    __syncthreads();
    if (tid < DIM) {
        float tot = (ps[0][tid] + ps[1][tid] + ps[2][tid] + ps[3][tid]) /
                    fmaxf((float)(hi - lo), 1.f);
        long idx = (long)g * (DIM * (NLAYERS + 1)) + rep * DIM + tid;
        if (f) ((float*)out)[idx] = tot;
        else   ((bf16*)out)[idx] = __float2bfloat16(tot);
    }
}

extern "C" void kernel_launch(void* const* d_in, const int* in_sizes, int n_in,
                              void* d_out, int out_size, void* d_ws, size_t ws_size,
                              hipStream_t stream) {
    static const int EXPECT[11] = {6400000, 2400000, 100000, 4096, 64,
                                   16384, 256, 256, 256, 16384, 256};
    int bad = (n_in == 11) ? -1 : 99;
    if (bad < 0)
        for (int i = 0; i < 11; i++)
            if (in_sizes[i] != EXPECT[i]) { bad = i; break; }
    if (bad >= 0) {
        k_diag<<<1, 64, 0, stream>>>((u32*)d_out, 3000.0f + 100.0f * (float)bad);
        return;
    }
    if (ws_size < WS_NEED_BYTES) {
        k_diag<<<1, 64, 0, stream>>>((u32*)d_out, 1000.0f + (float)(ws_size >> 20));
        return;
    }

    const void* x     = d_in[0];
    const int*  ei    = (const int*)d_in[1];
    const int*  batch = (const int*)d_in[2];

    float* ws = (float*)d_ws;
    float* gsum = ws + WS_GSUM;
    float* gsumsq = ws + WS_GSUMSQ;
    float* ab = ws + WS_AB;
    int*   flagp = (int*)(ws + WS_FLAG);
    float* WALL = ws + WS_WALL;
    float* agg = ws + WS_AGG;
    bf16*  h = (bf16*)(ws + WS_H);

    k_detect<<<1, 64, 0, stream>>>(x, flagp);
    k_convert<<<64, 256, 0, stream>>>(d_in[3], d_in[4], d_in[5], d_in[6],
                                      d_in[7], d_in[8], d_in[9], d_in[10], flagp, WALL);

    const int nb = 1024;
    k_embed<<<nb, 256, 0, stream>>>(x, flagp, WALL + OFF_WEMB, WALL + OFF_BEMB, h);
    k_pool<<<NG, 256, 0, stream>>>(h, batch, d_out, 0, flagp);
    for (int l = 0; l < NLAYERS; l++) {
        hipMemsetAsync(agg, 0, (size_t)N_NODES * DIM * sizeof(float), stream);
        hipMemsetAsync(gsum, 0, 128 * sizeof(float), stream);
        k_scatter<<<2048, 256, 0, stream>>>(ei, h, agg);
        k_gemm1<<<nb, 256, 0, stream>>>(h, agg, WALL + OFF_W1 + l * DIM * DIM,
                                        WALL + OFF_B1 + l * DIM, gsum, gsumsq);
        k_stats<<<1, 64, 0, stream>>>(gsum, gsumsq, WALL + OFF_GAMMA + l * DIM,
                                      WALL + OFF_BETA + l * DIM, ab);
        k_gemm2<<<nb, 256, 0, stream>>>(agg, h, WALL + OFF_W2 + l * DIM * DIM,
                                        WALL + OFF_B2 + l * DIM, ab);
        k_pool<<<NG, 256, 0, stream>>>(h, batch, d_out, l + 1, flagp);
    }
}